// Round 4
// baseline (50.875 us; speedup 1.0000x reference)
//
#include <hip/hip_runtime.h>
#include <hip/hip_bf16.h>

#define N 4096
#define D 768
#define LOG2E 1.44269504088896340736f
#define A_SCALE (20.0f * LOG2E)   // INV_T * log2(e): puts logits in base-2 domain
#define LN2 0.69314718055994530942f

typedef __attribute__((ext_vector_type(8))) short bf16x8;
typedef __attribute__((ext_vector_type(4))) float f32x4;

#define EXP2F(x) __builtin_amdgcn_exp2f(x)   // v_exp_f32: 2^x
#define LOG2F(x) __builtin_amdgcn_logf(x)    // v_log_f32: log2(x)

// global -> LDS direct DMA, 16B per lane, linear dest (wave base + lane*16)
#define GLDS16(g, l) __builtin_amdgcn_global_load_lds( \
    (const __attribute__((address_space(1))) void*)(g), \
    (__attribute__((address_space(3))) void*)(l), 16, 0, 0)

// ws layout (bytes):
//   [0,        6291456)  A bf16 (anchors * INV_T * log2e), N*D
//   [6291456, 12582912)  B bf16 (positives), N*D
//   [12582912,13107200)  partial[32][4096] float  (per colTile row sums of 2^s)
//   [13107200,13123584)  diagS[4096] float        (s2_jj, base-2 logit)
//   [13123584,13139968)  lastS[4096] float        (s2_{j,N-1})
//   [13139968,13140096)  blockSums[32] float

__device__ inline ushort f2bf(float x) {
    union { float f; unsigned u; } v; v.f = x;
    unsigned r = (v.u + 0x7fffu + ((v.u >> 16) & 1u)) >> 16;
    return (ushort)r;
}

__global__ void convert_kernel(const float* __restrict__ A, const float* __restrict__ B,
                               ushort* __restrict__ Abf, ushort* __restrict__ Bbf) {
    const int total = N * D / 4;
    int idx = blockIdx.x * blockDim.x + threadIdx.x;
    int stride = gridDim.x * blockDim.x;
    for (int i = idx; i < total; i += stride) {
        float4 a = ((const float4*)A)[i];
        float4 b = ((const float4*)B)[i];
        ushort4 av, bv;
        av.x = f2bf(a.x * A_SCALE); av.y = f2bf(a.y * A_SCALE);
        av.z = f2bf(a.z * A_SCALE); av.w = f2bf(a.w * A_SCALE);
        bv.x = f2bf(b.x); bv.y = f2bf(b.y); bv.z = f2bf(b.z); bv.w = f2bf(b.w);
        ((ushort4*)Abf)[i] = av;
        ((ushort4*)Bbf)[i] = bv;
    }
}

// 128x128 tile, BK=64, 4 waves (2x2), 2-phase double-buffered LDS (T3-minimum):
// stage t+1 into buf[cur^1] BEFORE computing tile t from buf[cur], then one
// __syncthreads (vmcnt(0)+barrier) per K-step — load latency hides under MFMA.
// LDS linear (global_load_lds); conflicts killed by XOR-swizzle applied to the
// global source chunk AND the fragment ds_read (rule #21).
__global__ __launch_bounds__(256) void gemm_kernel(const ushort* __restrict__ Abf,
                                                   const ushort* __restrict__ Bbf,
                                                   float* __restrict__ partial,
                                                   float* __restrict__ diagS,
                                                   float* __restrict__ lastS) {
    __shared__ __align__(16) ushort As[2][128 * 64];  // 2 x 16 KB
    __shared__ __align__(16) ushort Bs[2][128 * 64];  // 2 x 16 KB
    __shared__ float rowsum2[2][128];

    const int t    = threadIdx.x;
    const int bCol = blockIdx.x;
    const int bRow = blockIdx.y;
    const int lane = t & 63;
    const int w    = t >> 6;
    const int wr   = w >> 1;
    const int wc   = w & 1;
    const int lr   = lane & 15;
    const int hi   = lane >> 4;

    const int sr32 = t >> 3;            // 0..31
    const int sc   = t & 7;             // 0..7
    const int gcv  = sc ^ (sr32 & 7);   // swizzled global chunk
    const size_t aOff = (size_t)(bRow * 128 + sr32) * D + gcv * 8;
    const size_t bOff = (size_t)(bCol * 128 + sr32) * D + gcv * 8;

    f32x4 acc[4][4] = {};
    const int NT = D / 64;  // 12

    // prologue: stage tile 0 into buf 0 (only exposed load latency in the kernel)
    #pragma unroll
    for (int inst = 0; inst < 4; ++inst) {
        GLDS16(Abf + aOff + (size_t)inst * 32 * D, &As[0][inst * 2048 + w * 512]);
        GLDS16(Bbf + bOff + (size_t)inst * 32 * D, &Bs[0][inst * 2048 + w * 512]);
    }
    __syncthreads();

#define KSTEP(CUR, NXT, T) do {                                                       \
    if ((T) + 1 < NT) {                                                               \
        const int kn = ((T) + 1) * 64;                                                \
        _Pragma("unroll")                                                             \
        for (int inst = 0; inst < 4; ++inst) {                                        \
            GLDS16(Abf + aOff + (size_t)inst * 32 * D + kn,                           \
                   &As[NXT][inst * 2048 + w * 512]);                                  \
            GLDS16(Bbf + bOff + (size_t)inst * 32 * D + kn,                           \
                   &Bs[NXT][inst * 2048 + w * 512]);                                  \
        }                                                                             \
    }                                                                                 \
    bf16x8 af[2][4], bfr[2][4];                                                       \
    _Pragma("unroll")                                                                 \
    for (int kk = 0; kk < 2; ++kk) {                                                  \
        _Pragma("unroll")                                                             \
        for (int m = 0; m < 4; ++m) {                                                 \
            const int R = wr * 64 + m * 16 + lr;                                      \
            af[kk][m] = *(const bf16x8*)&As[CUR][R * 64 + (((kk * 4 + hi) ^ (lr & 7)) * 8)]; \
        }                                                                             \
        _Pragma("unroll")                                                             \
        for (int n = 0; n < 4; ++n) {                                                 \
            const int R = wc * 64 + n * 16 + lr;                                      \
            bfr[kk][n] = *(const bf16x8*)&Bs[CUR][R * 64 + (((kk * 4 + hi) ^ (lr & 7)) * 8)]; \
        }                                                                             \
    }                                                                                 \
    __builtin_amdgcn_s_setprio(1);                                                    \
    _Pragma("unroll")                                                                 \
    for (int kk = 0; kk < 2; ++kk)                                                    \
        _Pragma("unroll")                                                             \
        for (int m = 0; m < 4; ++m)                                                   \
            _Pragma("unroll")                                                         \
            for (int n = 0; n < 4; ++n)                                               \
                acc[m][n] = __builtin_amdgcn_mfma_f32_16x16x32_bf16(af[kk][m], bfr[kk][n], acc[m][n], 0, 0, 0); \
    __builtin_amdgcn_s_setprio(0);                                                    \
    __syncthreads();                                                                  \
} while (0)

    for (int tt = 0; tt < NT; tt += 2) {
        KSTEP(0, 1, tt);
        KSTEP(1, 0, tt + 1);
    }
#undef KSTEP

    // C/D layout (m89): col = lane&15 (= lr), row = hi*4 + reg
    const int rifb = hi * 4;

    if (bRow == bCol && wr == wc) {
        #pragma unroll
        for (int m = 0; m < 4; ++m)
            #pragma unroll
            for (int reg = 0; reg < 4; ++reg)
                if (lr == rifb + reg)
                    diagS[bRow * 128 + wr * 64 + m * 16 + rifb + reg] = acc[m][m][reg];
    }

    if (bCol == (N / 128 - 1) && wc == 1 && lr == 15) {
        #pragma unroll
        for (int m = 0; m < 4; ++m)
            #pragma unroll
            for (int reg = 0; reg < 4; ++reg)
                lastS[bRow * 128 + wr * 64 + m * 16 + rifb + reg] = acc[m][3][reg];
    }

    // 2^s over the tile, row-sum across the wave's 64 columns
    #pragma unroll
    for (int m = 0; m < 4; ++m) {
        #pragma unroll
        for (int reg = 0; reg < 4; ++reg) {
            float s = EXP2F(acc[m][0][reg]) + EXP2F(acc[m][1][reg]) +
                      EXP2F(acc[m][2][reg]) + EXP2F(acc[m][3][reg]);
            s += __shfl_xor(s, 1);
            s += __shfl_xor(s, 2);
            s += __shfl_xor(s, 4);
            s += __shfl_xor(s, 8);
            if (lr == 0) rowsum2[wc][wr * 64 + m * 16 + rifb + reg] = s;
        }
    }
    __syncthreads();
    if (t < 128) partial[(size_t)bCol * N + bRow * 128 + t] = rowsum2[0][t] + rowsum2[1][t];
}

__global__ void rowloss_kernel(const float* __restrict__ partial, const float* __restrict__ diagS,
                               const float* __restrict__ lastS, float* __restrict__ blockSums) {
    const int j = blockIdx.x * 128 + threadIdx.x;
    float rs = 0.0f;
    #pragma unroll
    for (int tI = 0; tI < 32; ++tI) rs += partial[(size_t)tI * N + j];
    float denom = rs + EXP2F(diagS[j]);
    float lossj = LN2 * (LOG2F(denom) - lastS[j]);
    #pragma unroll
    for (int off = 1; off < 64; off <<= 1) lossj += __shfl_xor(lossj, off);
    __shared__ float ws2[2];
    if ((threadIdx.x & 63) == 0) ws2[threadIdx.x >> 6] = lossj;
    __syncthreads();
    if (threadIdx.x == 0) blockSums[blockIdx.x] = ws2[0] + ws2[1];
}

__global__ void final_kernel(const float* __restrict__ blockSums, float* __restrict__ out) {
    float v = (threadIdx.x < 32) ? blockSums[threadIdx.x] : 0.0f;
    #pragma unroll
    for (int off = 1; off < 32; off <<= 1) v += __shfl_xor(v, off);
    if (threadIdx.x == 0) out[0] = v;
}

extern "C" void kernel_launch(void* const* d_in, const int* in_sizes, int n_in,
                              void* d_out, int out_size, void* d_ws, size_t ws_size,
                              hipStream_t stream) {
    const float* A = (const float*)d_in[0];
    const float* B = (const float*)d_in[1];
    float* out = (float*)d_out;
    char* ws = (char*)d_ws;

    ushort* Abf      = (ushort*)(ws);
    ushort* Bbf      = (ushort*)(ws + 6291456);
    float*  partial  = (float*)(ws + 12582912);
    float*  diagS    = (float*)(ws + 13107200);
    float*  lastS    = (float*)(ws + 13123584);
    float*  blockSums= (float*)(ws + 13139968);

    convert_kernel<<<1024, 256, 0, stream>>>(A, B, Abf, Bbf);
    gemm_kernel<<<dim3(32, 32), 256, 0, stream>>>(Abf, Bbf, partial, diagS, lastS);
    rowloss_kernel<<<32, 128, 0, stream>>>(partial, diagS, lastS, blockSums);
    final_kernel<<<1, 64, 0, stream>>>(blockSums, out);
}

// Round 5
// 48.849 us; speedup vs baseline: 1.0415x; 1.0415x over previous
//
#include <hip/hip_runtime.h>
#include <hip/hip_bf16.h>

#define N 4096
#define D 768
#define LOG2E 1.44269504088896340736f
#define A_SCALE (20.0f * LOG2E)   // INV_T * log2(e): puts logits in base-2 domain
#define LN2 0.69314718055994530942f

typedef __attribute__((ext_vector_type(8))) short bf16x8;
typedef __attribute__((ext_vector_type(4))) float f32x4;

#define EXP2F(x) __builtin_amdgcn_exp2f(x)   // v_exp_f32: 2^x
#define LOG2F(x) __builtin_amdgcn_logf(x)    // v_log_f32: log2(x)

// global -> LDS direct DMA, 16B per lane, linear dest (wave base + lane*16)
#define GLDS16(g, l) __builtin_amdgcn_global_load_lds( \
    (const __attribute__((address_space(1))) void*)(g), \
    (__attribute__((address_space(3))) void*)(l), 16, 0, 0)

// ws layout (bytes):
//   [0,        6291456)  A bf16 (anchors * INV_T * log2e), N*D
//   [6291456, 12582912)  B bf16 (positives), N*D
//   [12582912,13107200)  partial[32][4096] float  (per colTile row sums of 2^s)
//   [13107200,13123584)  diagS[4096] float        (s2_jj, base-2 logit)
//   [13123584,13139968)  lastS[4096] float        (s2_{j,N-1})
//   [13139968,13140096)  blockSums[32] float

__device__ inline ushort f2bf(float x) {
    union { float f; unsigned u; } v; v.f = x;
    unsigned r = (v.u + 0x7fffu + ((v.u >> 16) & 1u)) >> 16;
    return (ushort)r;
}

__global__ void convert_kernel(const float* __restrict__ A, const float* __restrict__ B,
                               ushort* __restrict__ Abf, ushort* __restrict__ Bbf) {
    const int total = N * D / 4;
    int idx = blockIdx.x * blockDim.x + threadIdx.x;
    int stride = gridDim.x * blockDim.x;
    for (int i = idx; i < total; i += stride) {
        float4 a = ((const float4*)A)[i];
        float4 b = ((const float4*)B)[i];
        ushort4 av, bv;
        av.x = f2bf(a.x * A_SCALE); av.y = f2bf(a.y * A_SCALE);
        av.z = f2bf(a.z * A_SCALE); av.w = f2bf(a.w * A_SCALE);
        bv.x = f2bf(b.x); bv.y = f2bf(b.y); bv.z = f2bf(b.z); bv.w = f2bf(b.w);
        ((ushort4*)Abf)[i] = av;
        ((ushort4*)Bbf)[i] = bv;
    }
}

// 128x128 tile, BK=64, 4 waves (2x2). T4 counted-vmcnt pipeline (depth 2):
// per iter, wait vmcnt(8) (tile t landed; tile t+1 STAYS in flight across the
// barrier), compute tile t, barrier, then stage tile t+2 into the freed buffer.
// Raw s_barrier (no implicit vmcnt-0 drain). Explicit lgkmcnt(0)+sched_barrier
// before the second barrier pins ds_read completion above the buffer overwrite
// (rule #18 / m152 race discipline).
__global__ __launch_bounds__(256) void gemm_kernel(const ushort* __restrict__ Abf,
                                                   const ushort* __restrict__ Bbf,
                                                   float* __restrict__ partial,
                                                   float* __restrict__ diagS,
                                                   float* __restrict__ lastS) {
    __shared__ __align__(16) ushort As[2][128 * 64];  // 2 x 16 KB
    __shared__ __align__(16) ushort Bs[2][128 * 64];  // 2 x 16 KB
    __shared__ float rowsum2[2][128];

    const int t    = threadIdx.x;
    const int bCol = blockIdx.x;
    const int bRow = blockIdx.y;
    const int lane = t & 63;
    const int w    = t >> 6;
    const int wr   = w >> 1;
    const int wc   = w & 1;
    const int lr   = lane & 15;
    const int hi   = lane >> 4;

    const int sr32 = t >> 3;            // 0..31
    const int sc   = t & 7;             // 0..7
    const int gcv  = sc ^ (sr32 & 7);   // swizzled global chunk
    const size_t aOff = (size_t)(bRow * 128 + sr32) * D + gcv * 8;
    const size_t bOff = (size_t)(bCol * 128 + sr32) * D + gcv * 8;

    f32x4 acc[4][4] = {};
    const int NT = D / 64;  // 12

#define STAGE(BUF, T) do {                                                            \
    const int kn_ = (T) * 64;                                                         \
    _Pragma("unroll")                                                                 \
    for (int inst = 0; inst < 4; ++inst) {                                            \
        GLDS16(Abf + aOff + (size_t)inst * 32 * D + kn_, &As[BUF][inst * 2048 + w * 512]); \
        GLDS16(Bbf + bOff + (size_t)inst * 32 * D + kn_, &Bs[BUF][inst * 2048 + w * 512]); \
    }                                                                                 \
} while (0)

// One pipeline iteration. VN: vmcnt immediate (8 = tile T landed, T+1 still in
// flight; 0 = full drain for the last tile). DOSTAGE: stage tile T+2 into CUR.
#define ITER(CUR, T, VN, DOSTAGE) do {                                                \
    asm volatile("s_waitcnt vmcnt(" #VN ")" ::: "memory");                            \
    __builtin_amdgcn_s_barrier();                                                     \
    __builtin_amdgcn_sched_barrier(0);                                                \
    bf16x8 af[2][4], bfr[2][4];                                                       \
    _Pragma("unroll")                                                                 \
    for (int kk = 0; kk < 2; ++kk) {                                                  \
        _Pragma("unroll")                                                             \
        for (int m = 0; m < 4; ++m) {                                                 \
            const int R = wr * 64 + m * 16 + lr;                                      \
            af[kk][m] = *(const bf16x8*)&As[CUR][R * 64 + (((kk * 4 + hi) ^ (lr & 7)) * 8)]; \
        }                                                                             \
        _Pragma("unroll")                                                             \
        for (int n = 0; n < 4; ++n) {                                                 \
            const int R = wc * 64 + n * 16 + lr;                                      \
            bfr[kk][n] = *(const bf16x8*)&Bs[CUR][R * 64 + (((kk * 4 + hi) ^ (lr & 7)) * 8)]; \
        }                                                                             \
    }                                                                                 \
    __builtin_amdgcn_s_setprio(1);                                                    \
    _Pragma("unroll")                                                                 \
    for (int kk = 0; kk < 2; ++kk)                                                    \
        _Pragma("unroll")                                                             \
        for (int m = 0; m < 4; ++m)                                                   \
            _Pragma("unroll")                                                         \
            for (int n = 0; n < 4; ++n)                                               \
                acc[m][n] = __builtin_amdgcn_mfma_f32_16x16x32_bf16(af[kk][m], bfr[kk][n], acc[m][n], 0, 0, 0); \
    __builtin_amdgcn_s_setprio(0);                                                    \
    asm volatile("s_waitcnt lgkmcnt(0)" ::: "memory");                                \
    __builtin_amdgcn_sched_barrier(0);                                                \
    __builtin_amdgcn_s_barrier();                                                     \
    __builtin_amdgcn_sched_barrier(0);                                                \
    if (DOSTAGE) STAGE(CUR, (T) + 2);                                                 \
} while (0)

    // prologue: tiles 0 and 1 in flight (16 outstanding vmem/wave)
    STAGE(0, 0);
    STAGE(1, 1);

    for (int tt = 0; tt < NT - 2; tt += 2) {   // tt = 0,2,4,6,8 -> iters 0..9
        ITER(0, tt,     8, 1);                 // stages tiles 2..11
        ITER(1, tt + 1, 8, 1);
    }
    ITER(0, NT - 2, 8, 0);                     // iter 10: tile 11 still in flight
    ITER(1, NT - 1, 0, 0);                     // iter 11: final drain
#undef ITER
#undef STAGE

    // C/D layout (m89): col = lane&15 (= lr), row = hi*4 + reg
    const int rifb = hi * 4;

    if (bRow == bCol && wr == wc) {
        #pragma unroll
        for (int m = 0; m < 4; ++m)
            #pragma unroll
            for (int reg = 0; reg < 4; ++reg)
                if (lr == rifb + reg)
                    diagS[bRow * 128 + wr * 64 + m * 16 + rifb + reg] = acc[m][m][reg];
    }

    if (bCol == (N / 128 - 1) && wc == 1 && lr == 15) {
        #pragma unroll
        for (int m = 0; m < 4; ++m)
            #pragma unroll
            for (int reg = 0; reg < 4; ++reg)
                lastS[bRow * 128 + wr * 64 + m * 16 + rifb + reg] = acc[m][3][reg];
    }

    // 2^s over the tile, row-sum across the wave's 64 columns
    #pragma unroll
    for (int m = 0; m < 4; ++m) {
        #pragma unroll
        for (int reg = 0; reg < 4; ++reg) {
            float s = EXP2F(acc[m][0][reg]) + EXP2F(acc[m][1][reg]) +
                      EXP2F(acc[m][2][reg]) + EXP2F(acc[m][3][reg]);
            s += __shfl_xor(s, 1);
            s += __shfl_xor(s, 2);
            s += __shfl_xor(s, 4);
            s += __shfl_xor(s, 8);
            if (lr == 0) rowsum2[wc][wr * 64 + m * 16 + rifb + reg] = s;
        }
    }
    __syncthreads();
    if (t < 128) partial[(size_t)bCol * N + bRow * 128 + t] = rowsum2[0][t] + rowsum2[1][t];
}

__global__ void rowloss_kernel(const float* __restrict__ partial, const float* __restrict__ diagS,
                               const float* __restrict__ lastS, float* __restrict__ blockSums) {
    const int j = blockIdx.x * 128 + threadIdx.x;
    float rs = 0.0f;
    #pragma unroll
    for (int tI = 0; tI < 32; ++tI) rs += partial[(size_t)tI * N + j];
    float denom = rs + EXP2F(diagS[j]);
    float lossj = LN2 * (LOG2F(denom) - lastS[j]);
    #pragma unroll
    for (int off = 1; off < 64; off <<= 1) lossj += __shfl_xor(lossj, off);
    __shared__ float ws2[2];
    if ((threadIdx.x & 63) == 0) ws2[threadIdx.x >> 6] = lossj;
    __syncthreads();
    if (threadIdx.x == 0) blockSums[blockIdx.x] = ws2[0] + ws2[1];
}

__global__ void final_kernel(const float* __restrict__ blockSums, float* __restrict__ out) {
    float v = (threadIdx.x < 32) ? blockSums[threadIdx.x] : 0.0f;
    #pragma unroll
    for (int off = 1; off < 32; off <<= 1) v += __shfl_xor(v, off);
    if (threadIdx.x == 0) out[0] = v;
}

extern "C" void kernel_launch(void* const* d_in, const int* in_sizes, int n_in,
                              void* d_out, int out_size, void* d_ws, size_t ws_size,
                              hipStream_t stream) {
    const float* A = (const float*)d_in[0];
    const float* B = (const float*)d_in[1];
    float* out = (float*)d_out;
    char* ws = (char*)d_ws;

    ushort* Abf      = (ushort*)(ws);
    ushort* Bbf      = (ushort*)(ws + 6291456);
    float*  partial  = (float*)(ws + 12582912);
    float*  diagS    = (float*)(ws + 13107200);
    float*  lastS    = (float*)(ws + 13123584);
    float*  blockSums= (float*)(ws + 13139968);

    convert_kernel<<<1024, 256, 0, stream>>>(A, B, Abf, Bbf);
    gemm_kernel<<<dim3(32, 32), 256, 0, stream>>>(Abf, Bbf, partial, diagS, lastS);
    rowloss_kernel<<<32, 128, 0, stream>>>(partial, diagS, lastS, blockSums);
    final_kernel<<<1, 64, 0, stream>>>(blockSums, out);
}

// Round 6
// 46.352 us; speedup vs baseline: 1.0976x; 1.0539x over previous
//
#include <hip/hip_runtime.h>
#include <hip/hip_bf16.h>

#define N 4096
#define D 768
#define LOG2E 1.44269504088896340736f
#define A_SCALE (20.0f * LOG2E)   // INV_T * log2(e): puts logits in base-2 domain
#define LN2 0.69314718055994530942f

typedef __attribute__((ext_vector_type(8))) short bf16x8;
typedef __attribute__((ext_vector_type(4))) float f32x4;

#define EXP2F(x) __builtin_amdgcn_exp2f(x)   // v_exp_f32: 2^x
#define LOG2F(x) __builtin_amdgcn_logf(x)    // v_log_f32: log2(x)

// global -> LDS direct DMA, 16B per lane, linear dest (wave base + lane*16)
#define GLDS16(g, l) __builtin_amdgcn_global_load_lds( \
    (const __attribute__((address_space(1))) void*)(g), \
    (__attribute__((address_space(3))) void*)(l), 16, 0, 0)

// ws layout (bytes):
//   [0,        6291456)  A bf16 (anchors * INV_T * log2e), N*D
//   [6291456, 12582912)  B bf16 (positives), N*D
//   [12582912,13107200)  partial[16][4096] float  (per colTile row sums of 2^s)
//   [13107200,13123584)  diagS[4096] float        (s2_jj, base-2 logit)
//   [13123584,13139968)  lastS[4096] float        (s2_{j,N-1})
//   [13139968,13140096)  blockSums[32] float

__device__ inline ushort f2bf(float x) {
    union { float f; unsigned u; } v; v.f = x;
    unsigned r = (v.u + 0x7fffu + ((v.u >> 16) & 1u)) >> 16;
    return (ushort)r;
}

__global__ void convert_kernel(const float* __restrict__ A, const float* __restrict__ B,
                               ushort* __restrict__ Abf, ushort* __restrict__ Bbf) {
    const int total = N * D / 4;
    int idx = blockIdx.x * blockDim.x + threadIdx.x;
    int stride = gridDim.x * blockDim.x;
    for (int i = idx; i < total; i += stride) {
        float4 a = ((const float4*)A)[i];
        float4 b = ((const float4*)B)[i];
        ushort4 av, bv;
        av.x = f2bf(a.x * A_SCALE); av.y = f2bf(a.y * A_SCALE);
        av.z = f2bf(a.z * A_SCALE); av.w = f2bf(a.w * A_SCALE);
        bv.x = f2bf(b.x); bv.y = f2bf(b.y); bv.z = f2bf(b.z); bv.w = f2bf(b.w);
        ((ushort4*)Abf)[i] = av;
        ((ushort4*)Bbf)[i] = bv;
    }
}

// 256x256 tile, BK=64, 8 waves (2M x 4N), per-wave 128x64 output = acc[8][4].
// T4 counted-vmcnt pipeline (depth 2, same verified schedule as R5): per iter
// wait vmcnt(8) (tile t landed; t+1 stays in flight across the barrier),
// compute tile t, lgkmcnt(0)+barrier, stage tile t+2 into the freed buffer.
// LDS linear (global_load_lds); conflicts killed by chunk-XOR swizzle applied
// to the global source AND the fragment ds_read (rule #21).
__global__ __launch_bounds__(512) void gemm_kernel(const ushort* __restrict__ Abf,
                                                   const ushort* __restrict__ Bbf,
                                                   float* __restrict__ partial,
                                                   float* __restrict__ diagS,
                                                   float* __restrict__ lastS) {
    __shared__ __align__(16) ushort As[2][256 * 64];  // 2 x 32 KB
    __shared__ __align__(16) ushort Bs[2][256 * 64];  // 2 x 32 KB
    __shared__ float rowsumL[4][256];                  // 4 KB

    const int t    = threadIdx.x;
    const int bCol = blockIdx.x;
    const int bRow = blockIdx.y;
    const int lane = t & 63;
    const int w    = t >> 6;      // wave 0..7
    const int wm   = w >> 2;      // wave M 0..1 (owns rows wm*128..+128)
    const int wn   = w & 3;       // wave N 0..3 (owns cols wn*64..+64)
    const int lr   = lane & 15;
    const int hi   = lane >> 4;

    // staging: thread t covers (row t>>3 of a 64-row round, 16B chunk t&7);
    // source chunk XOR-swizzled so linear LDS holds the swizzled image
    const int srow = t >> 3;            // 0..63
    const int sc   = t & 7;             // 0..7
    const int gcv  = sc ^ (srow & 7);   // swizzled global chunk
    const size_t aOff = (size_t)(bRow * 256 + srow) * D + gcv * 8;
    const size_t bOff = (size_t)(bCol * 256 + srow) * D + gcv * 8;

    f32x4 acc[8][4] = {};
    const int NT = D / 64;  // 12

#define STAGE(BUF, T) do {                                                            \
    const int kn_ = (T) * 64;                                                         \
    _Pragma("unroll")                                                                 \
    for (int r = 0; r < 4; ++r) {                                                     \
        GLDS16(Abf + aOff + (size_t)r * 64 * D + kn_, &As[BUF][(r * 64 + w * 8) * 64]); \
        GLDS16(Bbf + bOff + (size_t)r * 64 * D + kn_, &Bs[BUF][(r * 64 + w * 8) * 64]); \
    }                                                                                 \
} while (0)

// One pipeline iteration. VN: vmcnt immediate (8 = tile T landed, T+1 still in
// flight; 0 = full drain for the last tile). DOSTAGE: stage tile T+2 into CUR.
#define ITER(CUR, T, VN, DOSTAGE) do {                                                \
    asm volatile("s_waitcnt vmcnt(" #VN ")" ::: "memory");                            \
    __builtin_amdgcn_s_barrier();                                                     \
    __builtin_amdgcn_sched_barrier(0);                                                \
    _Pragma("unroll")                                                                 \
    for (int kk = 0; kk < 2; ++kk) {                                                  \
        bf16x8 af[8], bfr[4];                                                         \
        _Pragma("unroll")                                                             \
        for (int mf = 0; mf < 8; ++mf)                                                \
            af[mf] = *(const bf16x8*)&As[CUR][(wm * 128 + mf * 16 + lr) * 64 +        \
                                             (((kk * 4 + hi) ^ (lr & 7)) * 8)];       \
        _Pragma("unroll")                                                             \
        for (int nf = 0; nf < 4; ++nf)                                                \
            bfr[nf] = *(const bf16x8*)&Bs[CUR][(wn * 64 + nf * 16 + lr) * 64 +        \
                                              (((kk * 4 + hi) ^ (lr & 7)) * 8)];      \
        __builtin_amdgcn_s_setprio(1);                                                \
        _Pragma("unroll")                                                             \
        for (int mf = 0; mf < 8; ++mf)                                                \
            _Pragma("unroll")                                                         \
            for (int nf = 0; nf < 4; ++nf)                                            \
                acc[mf][nf] = __builtin_amdgcn_mfma_f32_16x16x32_bf16(af[mf], bfr[nf], acc[mf][nf], 0, 0, 0); \
        __builtin_amdgcn_s_setprio(0);                                                \
    }                                                                                 \
    asm volatile("s_waitcnt lgkmcnt(0)" ::: "memory");                                \
    __builtin_amdgcn_sched_barrier(0);                                                \
    __builtin_amdgcn_s_barrier();                                                     \
    __builtin_amdgcn_sched_barrier(0);                                                \
    if (DOSTAGE) STAGE(CUR, (T) + 2);                                                 \
} while (0)

    // prologue: tiles 0 and 1 in flight (16 outstanding vmem/wave)
    STAGE(0, 0);
    STAGE(1, 1);

    for (int tt = 0; tt < NT - 2; tt += 2) {   // T = 0..9, stages tiles 2..11
        ITER(0, tt,     8, 1);
        ITER(1, tt + 1, 8, 1);
    }
    ITER(0, NT - 2, 8, 0);                     // T=10: tile 11 still in flight
    ITER(1, NT - 1, 0, 0);                     // T=11: final drain
#undef ITER
#undef STAGE

    // C/D layout (m89): col = lane&15 (= lr), row = hi*4 + reg
    const int rifb = hi * 4;

    // diagonal capture: global row == global col. All acc indices compile-time
    // (rule #20); the frag-level match condition is wave-uniform.
    if (bRow == bCol) {
        #pragma unroll
        for (int mf = 0; mf < 8; ++mf)
            #pragma unroll
            for (int nf = 0; nf < 4; ++nf)
                if (wm * 128 + mf * 16 == wn * 64 + nf * 16) {
                    #pragma unroll
                    for (int reg = 0; reg < 4; ++reg)
                        if (lr == rifb + reg)
                            diagS[bRow * 256 + wm * 128 + mf * 16 + rifb + reg] = acc[mf][nf][reg];
                }
    }

    // last-column capture: col N-1 -> bCol==15, wn==3, nf==3, lr==15
    if (bCol == (N / 256 - 1) && wn == 3 && lr == 15) {
        #pragma unroll
        for (int mf = 0; mf < 8; ++mf)
            #pragma unroll
            for (int reg = 0; reg < 4; ++reg)
                lastS[bRow * 256 + wm * 128 + mf * 16 + rifb + reg] = acc[mf][3][reg];
    }

    // 2^s over the tile, row-sum across the wave's 64 columns
    #pragma unroll
    for (int mf = 0; mf < 8; ++mf) {
        #pragma unroll
        for (int reg = 0; reg < 4; ++reg) {
            float s = EXP2F(acc[mf][0][reg]) + EXP2F(acc[mf][1][reg]) +
                      EXP2F(acc[mf][2][reg]) + EXP2F(acc[mf][3][reg]);
            s += __shfl_xor(s, 1);
            s += __shfl_xor(s, 2);
            s += __shfl_xor(s, 4);
            s += __shfl_xor(s, 8);
            if (lr == 0) rowsumL[wn][wm * 128 + mf * 16 + rifb + reg] = s;
        }
    }
    __syncthreads();
    if (t < 256)
        partial[(size_t)bCol * N + bRow * 256 + t] =
            rowsumL[0][t] + rowsumL[1][t] + rowsumL[2][t] + rowsumL[3][t];
}

__global__ void rowloss_kernel(const float* __restrict__ partial, const float* __restrict__ diagS,
                               const float* __restrict__ lastS, float* __restrict__ blockSums) {
    const int j = blockIdx.x * 128 + threadIdx.x;
    float rs = 0.0f;
    #pragma unroll
    for (int tI = 0; tI < 16; ++tI) rs += partial[(size_t)tI * N + j];
    float denom = rs + EXP2F(diagS[j]);
    float lossj = LN2 * (LOG2F(denom) - lastS[j]);
    #pragma unroll
    for (int off = 1; off < 64; off <<= 1) lossj += __shfl_xor(lossj, off);
    __shared__ float ws2[2];
    if ((threadIdx.x & 63) == 0) ws2[threadIdx.x >> 6] = lossj;
    __syncthreads();
    if (threadIdx.x == 0) blockSums[blockIdx.x] = ws2[0] + ws2[1];
}

__global__ void final_kernel(const float* __restrict__ blockSums, float* __restrict__ out) {
    float v = (threadIdx.x < 32) ? blockSums[threadIdx.x] : 0.0f;
    #pragma unroll
    for (int off = 1; off < 32; off <<= 1) v += __shfl_xor(v, off);
    if (threadIdx.x == 0) out[0] = v;
}

extern "C" void kernel_launch(void* const* d_in, const int* in_sizes, int n_in,
                              void* d_out, int out_size, void* d_ws, size_t ws_size,
                              hipStream_t stream) {
    const float* A = (const float*)d_in[0];
    const float* B = (const float*)d_in[1];
    float* out = (float*)d_out;
    char* ws = (char*)d_ws;

    ushort* Abf      = (ushort*)(ws);
    ushort* Bbf      = (ushort*)(ws + 6291456);
    float*  partial  = (float*)(ws + 12582912);
    float*  diagS    = (float*)(ws + 13107200);
    float*  lastS    = (float*)(ws + 13123584);
    float*  blockSums= (float*)(ws + 13139968);

    convert_kernel<<<1024, 256, 0, stream>>>(A, B, Abf, Bbf);
    gemm_kernel<<<dim3(16, 16), 512, 0, stream>>>(Abf, Bbf, partial, diagS, lastS);
    rowloss_kernel<<<32, 128, 0, stream>>>(partial, diagS, lastS, blockSums);
    final_kernel<<<1, 64, 0, stream>>>(blockSums, out);
}